// Round 3
// baseline (4527.008 us; speedup 1.0000x reference)
//
#include <hip/hip_runtime.h>
#include <stdint.h>

#define T_LEN 256
#define BATCH 64
#define EDIM  512
#define HDIM  256      // hidden per direction
#define GDIM  1024     // 4*HDIM
#define KTAG  7
#define NEGV  -10000.0f

using u16 = unsigned short;
using u32 = unsigned int;

typedef short    bf16x8 __attribute__((ext_vector_type(8)));
typedef _Float16 f16x8  __attribute__((ext_vector_type(8)));
typedef float    f32x4  __attribute__((ext_vector_type(4)));

__device__ __forceinline__ float bflo(u32 u) { return __uint_as_float(u << 16); }
__device__ __forceinline__ float bfhi(u32 u) { return __uint_as_float(u & 0xffff0000u); }
__device__ __forceinline__ float bf2f(u16 u) { return __uint_as_float(((u32)u) << 16); }
__device__ __forceinline__ u16 f2bf(float f) {
    u32 x = __float_as_uint(f);
    u32 r = x + 0x7fffu + ((x >> 16) & 1u);   // round-to-nearest-even
    return (u16)(r >> 16);
}
__device__ __forceinline__ u32 pack2(float a, float b) {
    return (u32)f2bf(a) | ((u32)f2bf(b) << 16);
}
// fast sigmoid / tanh (rel err ~1e-5, far below bf16 input noise)
__device__ __forceinline__ float fsig(float x)  { return __builtin_amdgcn_rcpf(1.f + __expf(-x)); }
__device__ __forceinline__ float ftanh(float x) { return 1.f - 2.f * __builtin_amdgcn_rcpf(1.f + __expf(2.f * x)); }

// h-LDS chunk swizzle: row-stride 256 f16 would alias all rows to one bank group;
// XOR the 16B-chunk index with (row&7) -> even 8-per-bank spread on ds_read_b128.
__device__ __forceinline__ int hsw(int row, int j) {
    return (row * 32 + ((j >> 3) ^ (row & 7))) * 8 + (j & 7);
}

// ---------------- embedding gather+convert: x[tb][e] = bf16(emb[sent[tb]][e]) ----------------
__global__ __launch_bounds__(64) void embed_k(const int* __restrict__ sent,
                                              const float* __restrict__ emb,
                                              u16* __restrict__ X) {
    int tb = blockIdx.x;
    int tok = sent[tb];
    const float4* src = (const float4*)(emb + (size_t)tok * EDIM);
    float4 a = src[threadIdx.x * 2];
    float4 b = src[threadIdx.x * 2 + 1];
    uint4 o;
    o.x = pack2(a.x, a.y); o.y = pack2(a.z, a.w);
    o.z = pack2(b.x, b.y); o.w = pack2(b.z, b.w);
    ((uint4*)(X + (size_t)tb * EDIM))[threadIdx.x] = o;
}

// ---------------- convert w_ih f32 -> bf16, same layout [2][2][1024][512] ----------------
__global__ __launch_bounds__(256) void conv_wih(const float* __restrict__ W,
                                                u16* __restrict__ WB) {
    int g = blockIdx.x * 256 + threadIdx.x;          // 262144 groups of 8
    const float4* src = (const float4*)(W + (size_t)g * 8);
    float4 a = src[0], b = src[1];
    uint4 o;
    o.x = pack2(a.x, a.y); o.y = pack2(a.z, a.w);
    o.z = pack2(b.x, b.y); o.w = pack2(b.z, b.w);
    *(uint4*)(WB + (size_t)g * 8) = o;
}

// ---------------- convert w_hh f32 -> f16, same layout [4][1024][256] ----------------
__global__ __launch_bounds__(256) void conv_whh(const float* __restrict__ W,
                                                _Float16* __restrict__ WF) {
    int g = blockIdx.x * 256 + threadIdx.x;          // 131072 groups of 8
    const float4* src = (const float4*)(W + (size_t)g * 8);
    float4 a = src[0], b = src[1];
    f16x8 o = { (_Float16)a.x, (_Float16)a.y, (_Float16)a.z, (_Float16)a.w,
                (_Float16)b.x, (_Float16)b.y, (_Float16)b.z, (_Float16)b.w };
    *(f16x8*)(WF + (size_t)g * 8) = o;
}

// ------------- xg = x @ w_ih^T + b_ih + b_hh  (MFMA bf16, wave computes 16x64) -------------
__global__ __launch_bounds__(256) void gemm_xg(const u16* __restrict__ A,    // [16384][512] bf16
                                               const u16* __restrict__ W,    // [2][1024][512] bf16
                                               const float* __restrict__ Bih,// [2][1024] f32
                                               const float* __restrict__ Bhh,
                                               u16* __restrict__ XG) {       // [2][16384][1024] bf16
    const int d    = blockIdx.y;
    const int lane = threadIdx.x & 63;
    const int wv   = threadIdx.x >> 6;
    const int wid  = blockIdx.x * 4 + wv;       // 0..16383
    const int nj   = wid >> 10;                 // 0..15  (n-tile of 64)
    const int mi   = wid & 1023;                // 0..1023 (m-tile of 16)
    const int l15  = lane & 15;
    const int quad = lane >> 4;

    const u16* Wd  = W + (size_t)d * GDIM * EDIM;
    const u16* Ap  = A  + (size_t)(mi * 16 + l15) * EDIM + quad * 8;
    const u16* Bp0 = Wd + (size_t)(nj * 64 +  0 + l15) * EDIM + quad * 8;
    const u16* Bp1 = Wd + (size_t)(nj * 64 + 16 + l15) * EDIM + quad * 8;
    const u16* Bp2 = Wd + (size_t)(nj * 64 + 32 + l15) * EDIM + quad * 8;
    const u16* Bp3 = Wd + (size_t)(nj * 64 + 48 + l15) * EDIM + quad * 8;

    f32x4 acc0 = {0.f,0.f,0.f,0.f}, acc1 = acc0, acc2 = acc0, acc3 = acc0;
    #pragma unroll 4
    for (int kk = 0; kk < 16; ++kk) {
        bf16x8 a  = *(const bf16x8*)(Ap  + kk * 32);
        bf16x8 b0 = *(const bf16x8*)(Bp0 + kk * 32);
        bf16x8 b1 = *(const bf16x8*)(Bp1 + kk * 32);
        bf16x8 b2 = *(const bf16x8*)(Bp2 + kk * 32);
        bf16x8 b3 = *(const bf16x8*)(Bp3 + kk * 32);
        acc0 = __builtin_amdgcn_mfma_f32_16x16x32_bf16(a, b0, acc0, 0, 0, 0);
        acc1 = __builtin_amdgcn_mfma_f32_16x16x32_bf16(a, b1, acc1, 0, 0, 0);
        acc2 = __builtin_amdgcn_mfma_f32_16x16x32_bf16(a, b2, acc2, 0, 0, 0);
        acc3 = __builtin_amdgcn_mfma_f32_16x16x32_bf16(a, b3, acc3, 0, 0, 0);
    }

    u16* xgd = XG + (size_t)d * ((size_t)16384 * GDIM);
    const int row0 = mi * 16 + quad * 4;        // C/D: col=lane&15, row=(lane>>4)*4+reg
    f32x4 accs[4] = {acc0, acc1, acc2, acc3};
    #pragma unroll
    for (int t = 0; t < 4; ++t) {
        int col = nj * 64 + t * 16 + l15;
        float bias = Bih[d * GDIM + col] + Bhh[d * GDIM + col];
        #pragma unroll
        for (int r = 0; r < 4; ++r)
            xgd[(size_t)(row0 + r) * GDIM + col] = f2bf(accs[t][r] + bias);
    }
}

// ------------- recurrent scan, MFMA version -------------
// grid 32 = (dir 2) x (batch-slice 16 of M=4); block 1024 = 16 waves.
// Wave w owns gate-cols [64w, 64w+64): 4 n-tiles x 8 k-tiles of 16x16x32 f16 MFMA.
// kt 0..3 weight frags register-resident (64 VGPR), kt 4..7 streamed from L2
// each step (256 KB/block/step, half of the old kernel's traffic).
// h kept as f16 in swizzled LDS; batches are independent so blocks never talk.
#define MB4 4
__global__ __launch_bounds__(1024) void lstm_scan_mfma(
        const u16* __restrict__ XG,        // [2][16384][1024] bf16 (this layer)
        const _Float16* __restrict__ WF,   // [2][1024][256] f16 (this layer)
        const float* __restrict__ H0,      // [2][64][256] f32 (this layer)
        const float* __restrict__ C0,
        u16* __restrict__ XOUT) {          // [16384][512] bf16
    const int d    = blockIdx.x >> 4;
    const int mb   = blockIdx.x & 15;
    const int tid  = threadIdx.x;
    const int wv   = tid >> 6;
    const int lane = tid & 63;
    const int l15  = lane & 15;
    const int quad = lane >> 4;

    __shared__ float    Csh[MB4][1025];    // gate pre-acts (rows 0..3 valid), +1 pad
    __shared__ _Float16 Hsh[16 * 256];     // h (rows 0..3 valid, rest zero), swizzled

    // ---- resident B fragments: kt 0..3 ----
    const _Float16* Wd = WF + (size_t)d * (GDIM * HDIM);
    const _Float16* wp[4];
    #pragma unroll
    for (int nt = 0; nt < 4; ++nt)
        wp[nt] = Wd + (size_t)(wv * 64 + nt * 16 + l15) * HDIM + quad * 8;
    f16x8 Bf[4][4];
    #pragma unroll
    for (int nt = 0; nt < 4; ++nt)
        #pragma unroll
        for (int kt = 0; kt < 4; ++kt)
            Bf[nt][kt] = *(const f16x8*)(wp[nt] + kt * 32);

    // ---- init h (zero rows 4..15), c state ----
    for (int idx = tid; idx < 16 * 256; idx += 1024) Hsh[idx] = (_Float16)0.f;
    const int m  = tid & 3;                // batch row within block
    const int j  = tid >> 2;               // 0..255 hidden index
    const int b  = mb * MB4 + m;
    __syncthreads();
    Hsh[hsw(m, j)] = (_Float16)H0[((size_t)d * BATCH + b) * HDIM + j];
    float cstate   = C0[((size_t)d * BATCH + b) * HDIM + j];
    __syncthreads();

    const u16* xgb = XG + (size_t)d * ((size_t)16384 * GDIM);

    for (int s = 0; s < T_LEN; ++s) {
        const int t = d ? (T_LEN - 1 - s) : s;

        // ---- MFMA phase ----
        f32x4 acc[4];
        acc[0] = (f32x4){0.f,0.f,0.f,0.f}; acc[1] = acc[0];
        acc[2] = acc[0]; acc[3] = acc[0];
        #pragma unroll
        for (int kt = 0; kt < 8; ++kt) {
            f16x8 a = *(const f16x8*)&Hsh[(l15 * 32 + ((kt * 4 + quad) ^ (l15 & 7))) * 8];
            if (kt < 4) {
                #pragma unroll
                for (int nt = 0; nt < 4; ++nt)
                    acc[nt] = __builtin_amdgcn_mfma_f32_16x16x32_f16(a, Bf[nt][kt], acc[nt], 0, 0, 0);
            } else {
                #pragma unroll
                for (int nt = 0; nt < 4; ++nt) {
                    f16x8 w = *(const f16x8*)(wp[nt] + kt * 32);   // streamed from L2
                    acc[nt] = __builtin_amdgcn_mfma_f32_16x16x32_f16(a, w, acc[nt], 0, 0, 0);
                }
            }
        }
        // C layout: col = lane&15, row = quad*4+reg -> valid batch rows live in quad 0
        if (quad == 0) {
            #pragma unroll
            for (int nt = 0; nt < 4; ++nt) {
                int col = wv * 64 + nt * 16 + l15;
                #pragma unroll
                for (int r = 0; r < 4; ++r)
                    Csh[r][col] = acc[nt][r];
            }
        }
        __syncthreads();

        // ---- gate/update phase: 1 h-value per thread ----
        {
            const u16* xgrow = xgb + ((size_t)t * BATCH + b) * GDIM;
            float pi = Csh[m][j]        + bf2f(xgrow[j]);
            float pf = Csh[m][256 + j]  + bf2f(xgrow[256 + j]);
            float pg = Csh[m][512 + j]  + bf2f(xgrow[512 + j]);
            float po = Csh[m][768 + j]  + bf2f(xgrow[768 + j]);
            float iv = fsig(pi), fv = fsig(pf), gv = ftanh(pg), ov = fsig(po);
            cstate = fv * cstate + iv * gv;
            float h = ov * ftanh(cstate);
            Hsh[hsw(m, j)] = (_Float16)h;
            XOUT[((size_t)t * BATCH + b) * EDIM + d * HDIM + j] = f2bf(h);
        }
        __syncthreads();
    }
}

// ------------- feats[tb][k] = x[tb] . w_out[k] + b_out[k]  (one wave per tb) -------------
__global__ __launch_bounds__(64) void feats_k(const u16* __restrict__ X,      // [16384][512] bf16
                                              const float* __restrict__ Wout, // [7][512] f32
                                              const float* __restrict__ Bout, // [7] f32
                                              float* __restrict__ F) {        // [16384][8] f32
    int tb = blockIdx.x, lane = threadIdx.x;
    uint4 xv = ((const uint4*)(X + (size_t)tb * EDIM))[lane];   // 8 bf16 of x
    float xf[8];
    xf[0] = bflo(xv.x); xf[1] = bfhi(xv.x); xf[2] = bflo(xv.y); xf[3] = bfhi(xv.y);
    xf[4] = bflo(xv.z); xf[5] = bfhi(xv.z); xf[6] = bflo(xv.w); xf[7] = bfhi(xv.w);
    #pragma unroll
    for (int k = 0; k < KTAG; ++k) {
        const float4* wpo = (const float4*)(Wout + (size_t)k * EDIM) + lane * 2;
        float4 wa = wpo[0], wb = wpo[1];
        float p = 0.0f;
        p = fmaf(xf[0], wa.x, p); p = fmaf(xf[1], wa.y, p);
        p = fmaf(xf[2], wa.z, p); p = fmaf(xf[3], wa.w, p);
        p = fmaf(xf[4], wb.x, p); p = fmaf(xf[5], wb.y, p);
        p = fmaf(xf[6], wb.z, p); p = fmaf(xf[7], wb.w, p);
        #pragma unroll
        for (int off = 32; off > 0; off >>= 1) p += __shfl_xor(p, off, 64);
        if (lane == 0) F[tb * 8 + k] = p + Bout[k];
    }
}

// ------------- Viterbi: one wave, lane = batch; sequential over T -------------
__global__ __launch_bounds__(64) void viterbi_k(const float* __restrict__ F,
                                                const float* __restrict__ Trans, // [7][7] next,prev
                                                int* __restrict__ BPS,           // [256][64][8]
                                                float* __restrict__ OUT) {       // 16448 floats
    int b = threadIdx.x;
    float tr[KTAG][KTAG];
    #pragma unroll
    for (int n = 0; n < KTAG; ++n)
        #pragma unroll
        for (int p = 0; p < KTAG; ++p)
            tr[n][p] = Trans[n * KTAG + p];

    float v[KTAG];
    #pragma unroll
    for (int k = 0; k < KTAG; ++k) v[k] = (k == 5) ? 0.0f : NEGV;  // START=5

    for (int t = 0; t < T_LEN; ++t) {
        int base = (t * BATCH + b) * 8;
        float nv[KTAG];
        #pragma unroll
        for (int n = 0; n < KTAG; ++n) {
            float best = v[0] + tr[n][0]; int bi = 0;
            #pragma unroll
            for (int p = 1; p < KTAG; ++p) {
                float s = v[p] + tr[n][p];
                if (s > best) { best = s; bi = p; }   // strict > == np.argmax first-max
            }
            BPS[base + n] = bi;
            nv[n] = best + F[base + n];
        }
        #pragma unroll
        for (int n = 0; n < KTAG; ++n) v[n] = nv[n];
    }
    float bs = v[0] + tr[6][0]; int tag = 0;          // STOP=6
    #pragma unroll
    for (int k = 1; k < KTAG; ++k) {
        float s = v[k] + tr[6][k];
        if (s > bs) { bs = s; tag = k; }
    }
    OUT[T_LEN * BATCH + b] = bs;                      // path_score [B]
    for (int t = T_LEN - 1; t >= 0; --t) {
        OUT[(size_t)b * T_LEN + t] = (float)tag;      // best_path [B][T]
        tag = BPS[(t * BATCH + b) * 8 + tag];
    }
}

extern "C" void kernel_launch(void* const* d_in, const int* in_sizes, int n_in,
                              void* d_out, int out_size, void* d_ws, size_t ws_size,
                              hipStream_t stream) {
    const int*   sent  = (const int*)d_in[0];
    const float* emb   = (const float*)d_in[1];   // [50000][512]
    const float* w_ih  = (const float*)d_in[2];   // [2][2][1024][512]
    const float* w_hh  = (const float*)d_in[3];   // [2][2][1024][256]
    const float* b_ih  = (const float*)d_in[4];   // [2][2][1024]
    const float* b_hh  = (const float*)d_in[5];
    const float* w_out = (const float*)d_in[6];   // [7][512]
    const float* b_out = (const float*)d_in[7];   // [7]
    const float* trans = (const float*)d_in[8];   // [7][7]
    const float* h0    = (const float*)d_in[9];   // [4][64][256]
    const float* c0    = (const float*)d_in[10];
    float* out = (float*)d_out;

    char* ws = (char*)d_ws;
    u16*      xg    = (u16*)(ws);                        // 64 MB  [2][16384][1024] bf16
    u16*      x     = (u16*)(ws + 67108864);             // 16 MB  [16384][512] bf16
    u16*      wihB  = (u16*)(ws + 67108864 + 16777216);  // 4 MB   bf16 w_ih
    _Float16* wf16  = (_Float16*)(ws + 67108864 + 20971520); // 2 MB f16 w_hh
    float*    feats = (float*)(ws + 67108864 + 23068672);    // 512 KB
    int*      bps   = (int*)(ws + 67108864 + 23592960);      // 512 KB

    embed_k<<<16384, 64, 0, stream>>>(sent, emb, x);
    conv_wih<<<1024, 256, 0, stream>>>(w_ih, wihB);
    conv_whh<<<512, 256, 0, stream>>>(w_hh, wf16);

    for (int l = 0; l < 2; ++l) {
        gemm_xg<<<dim3(4096, 2), 256, 0, stream>>>(
            x, wihB + (size_t)l * 2 * GDIM * EDIM,
            b_ih + (size_t)l * 2 * GDIM, b_hh + (size_t)l * 2 * GDIM, xg);
        lstm_scan_mfma<<<32, 1024, 0, stream>>>(
            xg, wf16 + (size_t)l * 2 * GDIM * HDIM,
            h0 + (size_t)l * 2 * BATCH * HDIM, c0 + (size_t)l * 2 * BATCH * HDIM, x);
    }

    feats_k<<<16384, 64, 0, stream>>>(x, w_out, b_out, feats);
    viterbi_k<<<1, 64, 0, stream>>>(feats, trans, bps, out);
}

// Round 4
// 2359.822 us; speedup vs baseline: 1.9184x; 1.9184x over previous
//
#include <hip/hip_runtime.h>
#include <stdint.h>

#define T_LEN 256
#define BATCH 64
#define EDIM  512
#define HDIM  256      // hidden per direction
#define GDIM  1024     // 4*HDIM
#define KTAG  7
#define NEGV  -10000.0f

using u16 = unsigned short;
using u32 = unsigned int;
using u64 = unsigned long long;

typedef short    bf16x8 __attribute__((ext_vector_type(8)));
typedef _Float16 f16x8  __attribute__((ext_vector_type(8)));
typedef _Float16 f16x2  __attribute__((ext_vector_type(2)));
typedef float    f32x4  __attribute__((ext_vector_type(4)));

__device__ __forceinline__ float bflo(u32 u) { return __uint_as_float(u << 16); }
__device__ __forceinline__ float bfhi(u32 u) { return __uint_as_float(u & 0xffff0000u); }
__device__ __forceinline__ float bf2f(u16 u) { return __uint_as_float(((u32)u) << 16); }
__device__ __forceinline__ u16 f2bf(float f) {
    u32 x = __float_as_uint(f);
    u32 r = x + 0x7fffu + ((x >> 16) & 1u);   // round-to-nearest-even
    return (u16)(r >> 16);
}
__device__ __forceinline__ u32 pack2(float a, float b) {
    return (u32)f2bf(a) | ((u32)f2bf(b) << 16);
}
// fast sigmoid / tanh (rel err ~1e-5, far below bf16 input noise)
__device__ __forceinline__ float fsig(float x)  { return __builtin_amdgcn_rcpf(1.f + __expf(-x)); }
__device__ __forceinline__ float ftanh(float x) { return 1.f - 2.f * __builtin_amdgcn_rcpf(1.f + __expf(2.f * x)); }

__device__ __forceinline__ float fdot2_(f16x2 a, f16x2 b, float c) {
#if __has_builtin(__builtin_amdgcn_fdot2)
    return __builtin_amdgcn_fdot2(a, b, c, false);   // v_dot2_f32_f16
#else
    return fmaf((float)a.x, (float)b.x, fmaf((float)a.y, (float)b.y, c));
#endif
}

// ---------------- embedding gather+convert: x[tb][e] = bf16(emb[sent[tb]][e]) ----------------
__global__ __launch_bounds__(64) void embed_k(const int* __restrict__ sent,
                                              const float* __restrict__ emb,
                                              u16* __restrict__ X) {
    int tb = blockIdx.x;
    int tok = sent[tb];
    const float4* src = (const float4*)(emb + (size_t)tok * EDIM);
    float4 a = src[threadIdx.x * 2];
    float4 b = src[threadIdx.x * 2 + 1];
    uint4 o;
    o.x = pack2(a.x, a.y); o.y = pack2(a.z, a.w);
    o.z = pack2(b.x, b.y); o.w = pack2(b.z, b.w);
    ((uint4*)(X + (size_t)tb * EDIM))[threadIdx.x] = o;
}

// ---------------- convert w_ih f32 -> bf16, same layout [2][2][1024][512] ----------------
__global__ __launch_bounds__(256) void conv_wih(const float* __restrict__ W,
                                                u16* __restrict__ WB) {
    int g = blockIdx.x * 256 + threadIdx.x;          // 262144 groups of 8
    const float4* src = (const float4*)(W + (size_t)g * 8);
    float4 a = src[0], b = src[1];
    uint4 o;
    o.x = pack2(a.x, a.y); o.y = pack2(a.z, a.w);
    o.z = pack2(b.x, b.y); o.w = pack2(b.z, b.w);
    *(uint4*)(WB + (size_t)g * 8) = o;
}

// ------ repack+convert w_hh [4][1024][256] f32 -> [4][32][1024][8] f16 (k-blocked) ------
__global__ __launch_bounds__(256) void repack_whh(const float* __restrict__ Whh,
                                                  _Float16* __restrict__ WT) {
    int g = blockIdx.x * 256 + threadIdx.x;     // 4*32*1024 = 131072 groups of 8
    int ld  = g >> 15;                          // layer*2+dir
    int rem = g & 32767;
    int kb  = rem >> 10;                        // 0..31
    int j   = rem & 1023;                       // gate row
    const float4* src = (const float4*)(Whh + ((size_t)(ld * GDIM + j)) * HDIM + kb * 8);
    float4 a = src[0], b = src[1];
    f16x8 o = { (_Float16)a.x, (_Float16)a.y, (_Float16)a.z, (_Float16)a.w,
                (_Float16)b.x, (_Float16)b.y, (_Float16)b.z, (_Float16)b.w };
    *(f16x8*)(WT + (size_t)g * 8) = o;
}

// ------------- xg = x @ w_ih^T + b_ih + b_hh  (MFMA bf16, wave computes 64x64) -------------
__global__ __launch_bounds__(256, 4) void gemm_xg(const u16* __restrict__ A,    // [16384][512] bf16
                                                  const u16* __restrict__ W,    // [2][1024][512] bf16
                                                  const float* __restrict__ Bih,// [2][1024] f32
                                                  const float* __restrict__ Bhh,
                                                  u16* __restrict__ XG) {       // [2][16384][1024] bf16
    const int d    = blockIdx.y;
    const int lane = threadIdx.x & 63;
    const int wv   = threadIdx.x >> 6;
    const int wid  = blockIdx.x * 4 + wv;       // 0..4095
    const int mi   = wid & 255;                 // 64-row tile
    const int nj   = wid >> 8;                  // 0..15, 64-col tile
    const int l15  = lane & 15;
    const int quad = lane >> 4;

    const u16* Wd = W + (size_t)d * GDIM * EDIM;
    const u16* Ap[4];
    const u16* Bp[4];
    #pragma unroll
    for (int i = 0; i < 4; ++i) {
        Ap[i] = A  + (size_t)(mi * 64 + i * 16 + l15) * EDIM + quad * 8;
        Bp[i] = Wd + (size_t)(nj * 64 + i * 16 + l15) * EDIM + quad * 8;
    }

    f32x4 acc[4][4];
    #pragma unroll
    for (int mt = 0; mt < 4; ++mt)
        #pragma unroll
        for (int nt = 0; nt < 4; ++nt)
            acc[mt][nt] = (f32x4){0.f, 0.f, 0.f, 0.f};

    for (int kk = 0; kk < 16; ++kk) {
        bf16x8 av[4], bv[4];
        #pragma unroll
        for (int i = 0; i < 4; ++i) {
            av[i] = *(const bf16x8*)(Ap[i] + kk * 32);
            bv[i] = *(const bf16x8*)(Bp[i] + kk * 32);
        }
        #pragma unroll
        for (int mt = 0; mt < 4; ++mt)
            #pragma unroll
            for (int nt = 0; nt < 4; ++nt)
                acc[mt][nt] = __builtin_amdgcn_mfma_f32_16x16x32_bf16(av[mt], bv[nt], acc[mt][nt], 0, 0, 0);
    }

    u16* xgd = XG + (size_t)d * ((size_t)16384 * GDIM);
    #pragma unroll
    for (int nt = 0; nt < 4; ++nt) {
        int col = nj * 64 + nt * 16 + l15;          // C/D: col=lane&15, row=quad*4+reg
        float bias = Bih[d * GDIM + col] + Bhh[d * GDIM + col];
        #pragma unroll
        for (int mt = 0; mt < 4; ++mt) {
            int row0 = mi * 64 + mt * 16 + quad * 4;
            #pragma unroll
            for (int r = 0; r < 4; ++r)
                xgd[(size_t)(row0 + r) * GDIM + col] = f2bf(acc[mt][nt][r] + bias);
        }
    }
}

// ------------- recurrent scan: one block per (batch, dir); thread j = gate j -------------
// R2 topology (128 blocks = 128 CUs), but: f16 weights + h, v_dot2_f32_f16 (halves VALU),
// 8 weight loads in flight (128-VGPR budget), xg prefetched one step ahead.
__global__ __launch_bounds__(1024, 4) void lstm_scan(
        const u16* __restrict__ XG,        // [2][16384][1024] bf16 (this layer)
        const _Float16* __restrict__ WT,   // [2][32][1024][8] f16 repacked (this layer)
        const float* __restrict__ H0,      // [2][64][256] f32 (this layer)
        const float* __restrict__ C0,
        u16* __restrict__ XOUT) {          // [16384][512] bf16
    const int b = blockIdx.x & 63;
    const int d = blockIdx.x >> 6;
    const int j = threadIdx.x;

    __shared__ float act[GDIM];
    __shared__ __align__(16) _Float16 hsh[HDIM];

    const uint4* wp = (const uint4*)WT + (size_t)d * 32768 + j;   // [kb*8+u][j] -> wp[kk*1024]

    float cst = 0.0f;
    if (j < HDIM) {
        hsh[j] = (_Float16)H0[(d * BATCH + b) * HDIM + j];
        cst    = C0[(d * BATCH + b) * HDIM + j];
    }
    __syncthreads();

    const u16* xgp = XG + (size_t)d * ((size_t)16384 * GDIM) + (size_t)b * GDIM + j;
    u16 xv = xgp[(size_t)(d ? T_LEN - 1 : 0) * (BATCH * GDIM)];

    for (int s = 0; s < T_LEN; ++s) {
        const int t  = d ? (T_LEN - 1 - s) : s;
        const int sn = (s + 1 < T_LEN) ? s + 1 : s;
        const int tn = d ? (T_LEN - 1 - sn) : sn;
        u16 xnext = xgp[(size_t)tn * (BATCH * GDIM)];   // prefetch next step (HBM latency hidden)

        float g = bf2f(xv);
        #pragma unroll
        for (int kb = 0; kb < 4; ++kb) {
            uint4 w[8];
            #pragma unroll
            for (int u = 0; u < 8; ++u) w[u] = wp[(kb * 8 + u) * 1024];   // 8 L2 loads in flight
            #pragma unroll
            for (int u = 0; u < 8; ++u) {
                f16x8 hv = *(const f16x8*)&hsh[(kb * 8 + u) * 8];         // uniform -> broadcast
                g = fdot2_(__builtin_bit_cast(f16x2, w[u].x), (f16x2){hv[0], hv[1]}, g);
                g = fdot2_(__builtin_bit_cast(f16x2, w[u].y), (f16x2){hv[2], hv[3]}, g);
                g = fdot2_(__builtin_bit_cast(f16x2, w[u].z), (f16x2){hv[4], hv[5]}, g);
                g = fdot2_(__builtin_bit_cast(f16x2, w[u].w), (f16x2){hv[6], hv[7]}, g);
            }
        }
        act[j] = ((j >> 8) == 2) ? ftanh(g) : fsig(g);   // gate order i,f,g,o; wave-uniform branch
        __syncthreads();
        if (j < HDIM) {
            float iv = act[j], fv = act[HDIM + j], gv = act[2 * HDIM + j], ov = act[3 * HDIM + j];
            cst = fv * cst + iv * gv;
            float h = ov * ftanh(cst);
            hsh[j] = (_Float16)h;
            XOUT[((size_t)t * BATCH + b) * EDIM + d * HDIM + j] = f2bf(h);
        }
        __syncthreads();
        xv = xnext;
    }
}

// ------------- feats[tb][k] = x[tb] . w_out[k] + b_out[k]  (one wave per tb) -------------
__global__ __launch_bounds__(64) void feats_k(const u16* __restrict__ X,      // [16384][512] bf16
                                              const float* __restrict__ Wout, // [7][512] f32
                                              const float* __restrict__ Bout, // [7] f32
                                              float* __restrict__ F) {        // [16384][8] f32
    int tb = blockIdx.x, lane = threadIdx.x;
    uint4 xv = ((const uint4*)(X + (size_t)tb * EDIM))[lane];   // 8 bf16 of x
    float xf[8];
    xf[0] = bflo(xv.x); xf[1] = bfhi(xv.x); xf[2] = bflo(xv.y); xf[3] = bfhi(xv.y);
    xf[4] = bflo(xv.z); xf[5] = bfhi(xv.z); xf[6] = bflo(xv.w); xf[7] = bfhi(xv.w);
    #pragma unroll
    for (int k = 0; k < KTAG; ++k) {
        const float4* wpo = (const float4*)(Wout + (size_t)k * EDIM) + lane * 2;
        float4 wa = wpo[0], wb = wpo[1];
        float p = 0.0f;
        p = fmaf(xf[0], wa.x, p); p = fmaf(xf[1], wa.y, p);
        p = fmaf(xf[2], wa.z, p); p = fmaf(xf[3], wa.w, p);
        p = fmaf(xf[4], wb.x, p); p = fmaf(xf[5], wb.y, p);
        p = fmaf(xf[6], wb.z, p); p = fmaf(xf[7], wb.w, p);
        #pragma unroll
        for (int off = 32; off > 0; off >>= 1) p += __shfl_xor(p, off, 64);
        if (lane == 0) F[tb * 8 + k] = p + Bout[k];
    }
}

// ------------- Viterbi: one wave, lane = batch; byte-packed backpointers -------------
__global__ __launch_bounds__(64) void viterbi_k(const float* __restrict__ F,
                                                const float* __restrict__ Trans, // [7][7] next,prev
                                                u64* __restrict__ BP8,           // [256][64]
                                                float* __restrict__ OUT) {       // 16448 floats
    int b = threadIdx.x;
    float tr[KTAG][KTAG];
    #pragma unroll
    for (int n = 0; n < KTAG; ++n)
        #pragma unroll
        for (int p = 0; p < KTAG; ++p)
            tr[n][p] = Trans[n * KTAG + p];

    float v[KTAG];
    #pragma unroll
    for (int k = 0; k < KTAG; ++k) v[k] = (k == 5) ? 0.0f : NEGV;  // START=5

    float cf[KTAG], nf[KTAG];
    #pragma unroll
    for (int n = 0; n < KTAG; ++n) cf[n] = F[b * 8 + n];           // t=0

    for (int t = 0; t < T_LEN; ++t) {
        int tp = (t + 1 < T_LEN) ? t + 1 : t;
        #pragma unroll
        for (int n = 0; n < KTAG; ++n) nf[n] = F[((tp)*BATCH + b) * 8 + n];  // prefetch t+1

        u64 pk = 0;
        float nv[KTAG];
        #pragma unroll
        for (int n = 0; n < KTAG; ++n) {
            float best = v[0] + tr[n][0]; int bi = 0;
            #pragma unroll
            for (int p = 1; p < KTAG; ++p) {
                float s = v[p] + tr[n][p];
                if (s > best) { best = s; bi = p; }   // strict > == np.argmax first-max
            }
            pk |= ((u64)bi) << (8 * n);
            nv[n] = best + cf[n];
        }
        BP8[t * BATCH + b] = pk;
        #pragma unroll
        for (int n = 0; n < KTAG; ++n) { v[n] = nv[n]; cf[n] = nf[n]; }
    }
    float bs = v[0] + tr[6][0]; int tag = 0;          // STOP=6
    #pragma unroll
    for (int k = 1; k < KTAG; ++k) {
        float s = v[k] + tr[6][k];
        if (s > bs) { bs = s; tag = k; }
    }
    OUT[T_LEN * BATCH + b] = bs;                      // path_score [B]
    for (int t = T_LEN - 1; t >= 0; --t) {
        OUT[(size_t)b * T_LEN + t] = (float)tag;      // best_path [B][T]
        tag = (int)((BP8[t * BATCH + b] >> (8 * tag)) & 0xff);
    }
}

extern "C" void kernel_launch(void* const* d_in, const int* in_sizes, int n_in,
                              void* d_out, int out_size, void* d_ws, size_t ws_size,
                              hipStream_t stream) {
    const int*   sent  = (const int*)d_in[0];
    const float* emb   = (const float*)d_in[1];   // [50000][512]
    const float* w_ih  = (const float*)d_in[2];   // [2][2][1024][512]
    const float* w_hh  = (const float*)d_in[3];   // [2][2][1024][256]
    const float* b_ih  = (const float*)d_in[4];   // [2][2][1024]
    const float* b_hh  = (const float*)d_in[5];
    const float* w_out = (const float*)d_in[6];   // [7][512]
    const float* b_out = (const float*)d_in[7];   // [7]
    const float* trans = (const float*)d_in[8];   // [7][7]
    const float* h0    = (const float*)d_in[9];   // [4][64][256]
    const float* c0    = (const float*)d_in[10];
    float* out = (float*)d_out;

    char* ws = (char*)d_ws;
    u16*      xg    = (u16*)(ws);                        // 64 MB  [2][16384][1024] bf16
    u16*      x     = (u16*)(ws + 67108864);             // 16 MB  [16384][512] bf16
    u16*      wihB  = (u16*)(ws + 67108864 + 16777216);  // 4 MB   bf16 w_ih
    _Float16* wf16  = (_Float16*)(ws + 67108864 + 20971520); // 2 MB f16 repacked w_hh
    float*    feats = (float*)(ws + 67108864 + 23068672);    // 512 KB
    u64*      bp8   = (u64*)(ws + 67108864 + 23592960);      // 128 KB

    embed_k<<<16384, 64, 0, stream>>>(sent, emb, x);
    conv_wih<<<1024, 256, 0, stream>>>(w_ih, wihB);
    repack_whh<<<512, 256, 0, stream>>>(w_hh, wf16);

    for (int l = 0; l < 2; ++l) {
        gemm_xg<<<dim3(1024, 2), 256, 0, stream>>>(
            x, wihB + (size_t)l * 2 * GDIM * EDIM,
            b_ih + (size_t)l * 2 * GDIM, b_hh + (size_t)l * 2 * GDIM, xg);
        lstm_scan<<<128, 1024, 0, stream>>>(
            xg, wf16 + (size_t)l * 2 * 32 * GDIM * 8,
            h0 + (size_t)l * 2 * BATCH * HDIM, c0 + (size_t)l * 2 * BATCH * HDIM, x);
    }

    feats_k<<<16384, 64, 0, stream>>>(x, w_out, b_out, feats);
    viterbi_k<<<1, 64, 0, stream>>>(feats, trans, bp8, out);
}

// Round 6
// 1074.557 us; speedup vs baseline: 4.2129x; 2.1961x over previous
//
#include <hip/hip_runtime.h>
#include <stdint.h>

#define T_LEN 256
#define BATCH 64
#define EDIM  512
#define HDIM  256      // hidden per direction
#define GDIM  1024     // 4*HDIM
#define KTAG  7
#define NEGV  -10000.0f

using u16 = unsigned short;
using u32 = unsigned int;
using u64 = unsigned long long;

typedef short    bf16x8 __attribute__((ext_vector_type(8)));
typedef float    f32x4  __attribute__((ext_vector_type(4)));

__device__ __forceinline__ float bflo(u32 u) { return __uint_as_float(u << 16); }
__device__ __forceinline__ float bfhi(u32 u) { return __uint_as_float(u & 0xffff0000u); }
__device__ __forceinline__ float bf2f(u16 u) { return __uint_as_float(((u32)u) << 16); }
__device__ __forceinline__ u16 f2bf(float f) {
    u32 x = __float_as_uint(f);
    u32 r = x + 0x7fffu + ((x >> 16) & 1u);   // round-to-nearest-even
    return (u16)(r >> 16);
}
__device__ __forceinline__ u32 pack2(float a, float b) {
    return (u32)f2bf(a) | ((u32)f2bf(b) << 16);
}
// fast sigmoid / tanh (rel err ~1e-5, far below bf16 input noise)
__device__ __forceinline__ float fsig(float x)  { return __builtin_amdgcn_rcpf(1.f + __expf(-x)); }
__device__ __forceinline__ float ftanh(float x) { return 1.f - 2.f * __builtin_amdgcn_rcpf(1.f + __expf(2.f * x)); }

__device__ __forceinline__ int dot4i8(int a, int b, int c) {
#if __has_builtin(__builtin_amdgcn_sdot4)
    return __builtin_amdgcn_sdot4(a, b, c, false);     // v_dot4_i32_i8
#else
    c += (int)(signed char)(a & 0xff)         * (int)(signed char)(b & 0xff);
    c += (int)(signed char)((a >> 8) & 0xff)  * (int)(signed char)((b >> 8) & 0xff);
    c += (int)(signed char)((a >> 16) & 0xff) * (int)(signed char)((b >> 16) & 0xff);
    c += (int)(signed char)(a >> 24)          * (int)(signed char)(b >> 24);
    return c;
#endif
}

// ---------------- embedding gather+convert: x[tb][e] = bf16(emb[sent[tb]][e]) ----------------
__global__ __launch_bounds__(64) void embed_k(const int* __restrict__ sent,
                                              const float* __restrict__ emb,
                                              u16* __restrict__ X) {
    int tb = blockIdx.x;
    int tok = sent[tb];
    const float4* src = (const float4*)(emb + (size_t)tok * EDIM);
    float4 a = src[threadIdx.x * 2];
    float4 b = src[threadIdx.x * 2 + 1];
    uint4 o;
    o.x = pack2(a.x, a.y); o.y = pack2(a.z, a.w);
    o.z = pack2(b.x, b.y); o.w = pack2(b.z, b.w);
    ((uint4*)(X + (size_t)tb * EDIM))[threadIdx.x] = o;
}

// ---------------- convert w_ih f32 -> bf16, same layout [2][2][1024][512] ----------------
__global__ __launch_bounds__(256) void conv_wih(const float* __restrict__ W,
                                                u16* __restrict__ WB) {
    int g = blockIdx.x * 256 + threadIdx.x;          // 262144 groups of 8
    const float4* src = (const float4*)(W + (size_t)g * 8);
    float4 a = src[0], b = src[1];
    uint4 o;
    o.x = pack2(a.x, a.y); o.y = pack2(a.z, a.w);
    o.z = pack2(b.x, b.y); o.w = pack2(b.z, b.w);
    *(uint4*)(WB + (size_t)g * 8) = o;
}

// ---- quantize w_hh f32 [4][1024][256] -> int8 WQ[(((ld*4+r)*2+half)*8+c)*256+j] uint4 + SCL ----
// WQ uint4 (ld,r,half,c,j) holds wq[row=r*256+j][k = half*128 + c*16 .. +16).
// SCL[ld*1024+row] = rowmax / 127  (weight LSB; h scale applied at use)
__global__ __launch_bounds__(256) void repack_whh_i8(const float* __restrict__ Whh,
                                                     uint4* __restrict__ WQ,
                                                     float* __restrict__ SCL) {
    int g  = blockIdx.x * 256 + threadIdx.x;    // 4096 rows
    int ld = g >> 10, row = g & 1023;
    const float* src = Whh + ((size_t)ld * GDIM + row) * HDIM;
    float m = 1e-30f;
    for (int k4 = 0; k4 < 64; ++k4) {
        float4 w = ((const float4*)src)[k4];
        m = fmaxf(m, fmaxf(fmaxf(fabsf(w.x), fabsf(w.y)), fmaxf(fabsf(w.z), fabsf(w.w))));
    }
    float inv = 127.f / m;
    SCL[ld * GDIM + row] = m / 127.f;
    int r = row >> 8, j = row & 255;
    for (int c8 = 0; c8 < 16; ++c8) {           // 16-byte chunks
        u32 dw[4];
        #pragma unroll
        for (int d4 = 0; d4 < 4; ++d4) {
            u32 p = 0;
            #pragma unroll
            for (int bb = 0; bb < 4; ++bb) {
                float w = src[c8 * 16 + d4 * 4 + bb];
                int q = (int)rintf(w * inv);
                q = q > 127 ? 127 : (q < -127 ? -127 : q);
                p |= ((u32)(q & 0xff)) << (8 * bb);
            }
            dw[d4] = p;
        }
        int half = c8 >> 3, c = c8 & 7;
        WQ[(size_t)((((ld * 4 + r) * 2 + half) * 8 + c) * 256 + j)] =
            (uint4){dw[0], dw[1], dw[2], dw[3]};
    }
}

// ------------- xg = x @ w_ih^T + b_ih + b_hh  (MFMA bf16, wave computes 64x64) -------------
__global__ __launch_bounds__(256, 4) void gemm_xg(const u16* __restrict__ A,    // [16384][512] bf16
                                                  const u16* __restrict__ W,    // [2][1024][512] bf16
                                                  const float* __restrict__ Bih,// [2][1024] f32
                                                  const float* __restrict__ Bhh,
                                                  u16* __restrict__ XG) {       // [2][16384][1024] bf16
    const int d    = blockIdx.y;
    const int lane = threadIdx.x & 63;
    const int wv   = threadIdx.x >> 6;
    const int wid  = blockIdx.x * 4 + wv;       // 0..4095
    const int mi   = wid & 255;                 // 64-row tile
    const int nj   = wid >> 8;                  // 0..15, 64-col tile
    const int l15  = lane & 15;
    const int quad = lane >> 4;

    const u16* Wd = W + (size_t)d * GDIM * EDIM;
    const u16* Ap[4];
    const u16* Bp[4];
    #pragma unroll
    for (int i = 0; i < 4; ++i) {
        Ap[i] = A  + (size_t)(mi * 64 + i * 16 + l15) * EDIM + quad * 8;
        Bp[i] = Wd + (size_t)(nj * 64 + i * 16 + l15) * EDIM + quad * 8;
    }

    f32x4 acc[4][4];
    #pragma unroll
    for (int mt = 0; mt < 4; ++mt)
        #pragma unroll
        for (int nt = 0; nt < 4; ++nt)
            acc[mt][nt] = (f32x4){0.f, 0.f, 0.f, 0.f};

    for (int kk = 0; kk < 16; ++kk) {
        bf16x8 av[4], bv[4];
        #pragma unroll
        for (int i = 0; i < 4; ++i) {
            av[i] = *(const bf16x8*)(Ap[i] + kk * 32);
            bv[i] = *(const bf16x8*)(Bp[i] + kk * 32);
        }
        #pragma unroll
        for (int mt = 0; mt < 4; ++mt)
            #pragma unroll
            for (int nt = 0; nt < 4; ++nt)
                acc[mt][nt] = __builtin_amdgcn_mfma_f32_16x16x32_bf16(av[mt], bv[nt], acc[mt][nt], 0, 0, 0);
    }

    u16* xgd = XG + (size_t)d * ((size_t)16384 * GDIM);
    #pragma unroll
    for (int nt = 0; nt < 4; ++nt) {
        int col = nj * 64 + nt * 16 + l15;          // C/D: col=lane&15, row=quad*4+reg
        float bias = Bih[d * GDIM + col] + Bhh[d * GDIM + col];
        #pragma unroll
        for (int mt = 0; mt < 4; ++mt) {
            int row0 = mi * 64 + mt * 16 + quad * 4;
            #pragma unroll
            for (int r = 0; r < 4; ++r)
                xgd[(size_t)(row0 + r) * GDIM + col] = f2bf(acc[mt][nt][r] + bias);
        }
    }
}

// ------------- recurrent scan, int8 register-resident weights -------------
// 128 blocks = (d,b); 512 threads: j = tid&255, half = tid>>8 (K-half).
// Thread holds wq rows {j,256+j,512+j,768+j} for its K-half: 128 VGPRs, loaded once.
// h int8: step 0 scale 4/127 (random h0), steps>=1 scale 1/127 (|h|<1 strictly).
__global__ __launch_bounds__(512, 2) void lstm_scan_i8(
        const u16* __restrict__ XG,        // [2][16384][1024] bf16 (this layer)
        const uint4* __restrict__ WQ,      // this layer's int8 slice (base at ld=2l)
        const float* __restrict__ SCL,     // [2][1024] weight LSB
        const float* __restrict__ H0,      // [2][64][256] f32
        const float* __restrict__ C0,
        u16* __restrict__ XOUT) {          // [16384][512] bf16
    const int b    = blockIdx.x & 63;
    const int d    = blockIdx.x >> 6;
    const int tid  = threadIdx.x;
    const int j    = tid & 255;
    const int half = tid >> 8;

    __shared__ uint4 hq[2][16];            // double-buffered int8 h (2 x 256 B)
    __shared__ float ps[4][256];           // half1 integer partials (as exact f32)

    // ---- load weights into registers (coalesced: lane-adjacent j) ----
    uint4 Wr[4][8];
    #pragma unroll
    for (int r = 0; r < 4; ++r)
        #pragma unroll
        for (int c = 0; c < 8; ++c)
            Wr[r][c] = WQ[(size_t)((((d * 4 + r) * 2 + half) * 8 + c) * 256 + j)];
    float scl[4];
    #pragma unroll
    for (int r = 0; r < 4; ++r) scl[r] = SCL[d * GDIM + r * 256 + j];

    // ---- init state ----
    float cst = 0.0f;
    if (half == 0) {
        float h0v = H0[((size_t)d * BATCH + b) * HDIM + j];
        cst       = C0[((size_t)d * BATCH + b) * HDIM + j];
        int q = (int)rintf(h0v * 31.75f);                  // scale 127/4 (|h0| can exceed 1)
        q = q > 127 ? 127 : (q < -127 ? -127 : q);
        ((signed char*)hq)[j] = (signed char)q;            // buffer 0
    }
    __syncthreads();

    const u16* xgp = XG + (size_t)d * ((size_t)16384 * GDIM) + (size_t)b * GDIM + j;
    // 2-deep xg prefetch pipeline (covers ~900cyc HBM latency)
    u16 xa[4], xb2[4];
    if (half == 0) {
        int t0 = d ? T_LEN - 1 : 0;
        int t1 = d ? T_LEN - 2 : 1;
        #pragma unroll
        for (int r = 0; r < 4; ++r) xa[r]  = xgp[(size_t)t0 * (BATCH * GDIM) + r * 256];
        #pragma unroll
        for (int r = 0; r < 4; ++r) xb2[r] = xgp[(size_t)t1 * (BATCH * GDIM) + r * 256];
    }

    float hs = 4.f / 127.f;                // h LSB for this step's input h
    int cur = 0;
    for (int s = 0; s < T_LEN; ++s) {
        const int t = d ? (T_LEN - 1 - s) : s;
        // prefetch xg for s+2
        u16 xc[4];
        if (half == 0) {
            int s2 = (s + 2 < T_LEN) ? s + 2 : T_LEN - 1;
            int t2 = d ? (T_LEN - 1 - s2) : s2;
            #pragma unroll
            for (int r = 0; r < 4; ++r) xc[r] = xgp[(size_t)t2 * (BATCH * GDIM) + r * 256];
        }

        // read own K-half of h (wave-uniform addresses -> broadcast, no conflicts)
        uint4 hv[8];
        const uint4* hb = &hq[cur][half * 8];
        #pragma unroll
        for (int c = 0; c < 8; ++c) hv[c] = hb[c];

        int acc0 = 0, acc1 = 0, acc2 = 0, acc3 = 0;        // 4 independent chains
        #pragma unroll
        for (int c = 0; c < 8; ++c) {
            acc0 = dot4i8(Wr[0][c].x, hv[c].x, acc0);
            acc0 = dot4i8(Wr[0][c].y, hv[c].y, acc0);
            acc0 = dot4i8(Wr[0][c].z, hv[c].z, acc0);
            acc0 = dot4i8(Wr[0][c].w, hv[c].w, acc0);
            acc1 = dot4i8(Wr[1][c].x, hv[c].x, acc1);
            acc1 = dot4i8(Wr[1][c].y, hv[c].y, acc1);
            acc1 = dot4i8(Wr[1][c].z, hv[c].z, acc1);
            acc1 = dot4i8(Wr[1][c].w, hv[c].w, acc1);
            acc2 = dot4i8(Wr[2][c].x, hv[c].x, acc2);
            acc2 = dot4i8(Wr[2][c].y, hv[c].y, acc2);
            acc2 = dot4i8(Wr[2][c].z, hv[c].z, acc2);
            acc2 = dot4i8(Wr[2][c].w, hv[c].w, acc2);
            acc3 = dot4i8(Wr[3][c].x, hv[c].x, acc3);
            acc3 = dot4i8(Wr[3][c].y, hv[c].y, acc3);
            acc3 = dot4i8(Wr[3][c].z, hv[c].z, acc3);
            acc3 = dot4i8(Wr[3][c].w, hv[c].w, acc3);
        }
        if (half == 1) {                                   // |acc| < 2^22: f32-exact
            ps[0][j] = (float)acc0; ps[1][j] = (float)acc1;
            ps[2][j] = (float)acc2; ps[3][j] = (float)acc3;
        }
        __syncthreads();                                   // partials + h reads done
        if (half == 0) {
            float g0 = bf2f(xa[0]) + ((float)acc0 + ps[0][j]) * (scl[0] * hs);
            float g1 = bf2f(xa[1]) + ((float)acc1 + ps[1][j]) * (scl[1] * hs);
            float g2 = bf2f(xa[2]) + ((float)acc2 + ps[2][j]) * (scl[2] * hs);
            float g3 = bf2f(xa[3]) + ((float)acc3 + ps[3][j]) * (scl[3] * hs);
            float iv = fsig(g0), fv = fsig(g1), gv = ftanh(g2), ov = fsig(g3);
            cst = fv * cst + iv * gv;
            float h = ov * ftanh(cst);
            XOUT[((size_t)t * BATCH + b) * EDIM + d * HDIM + j] = f2bf(h);
            int q = (int)rintf(h * 127.f);                 // |h|<1: scale 1/127
            q = q > 127 ? 127 : (q < -127 ? -127 : q);
            ((signed char*)hq)[(cur ^ 1) * 256 + j] = (signed char)q;
            #pragma unroll
            for (int r = 0; r < 4; ++r) { xa[r] = xb2[r]; xb2[r] = xc[r]; }
        }
        __syncthreads();                                   // new hq visible
        cur ^= 1;
        hs = 1.f / 127.f;                                  // from step 1 on
    }
}

// ------------- feats[tb][k] = x[tb] . w_out[k] + b_out[k]  (one wave per tb) -------------
__global__ __launch_bounds__(64) void feats_k(const u16* __restrict__ X,      // [16384][512] bf16
                                              const float* __restrict__ Wout, // [7][512] f32
                                              const float* __restrict__ Bout, // [7] f32
                                              float* __restrict__ F) {        // [16384][8] f32
    int tb = blockIdx.x, lane = threadIdx.x;
    uint4 xv = ((const uint4*)(X + (size_t)tb * EDIM))[lane];   // 8 bf16 of x
    float xf[8];
    xf[0] = bflo(xv.x); xf[1] = bfhi(xv.x); xf[2] = bflo(xv.y); xf[3] = bfhi(xv.y);
    xf[4] = bflo(xv.z); xf[5] = bfhi(xv.z); xf[6] = bflo(xv.w); xf[7] = bfhi(xv.w);
    #pragma unroll
    for (int k = 0; k < KTAG; ++k) {
        const float4* wpo = (const float4*)(Wout + (size_t)k * EDIM) + lane * 2;
        float4 wa = wpo[0], wb = wpo[1];
        float p = 0.0f;
        p = fmaf(xf[0], wa.x, p); p = fmaf(xf[1], wa.y, p);
        p = fmaf(xf[2], wa.z, p); p = fmaf(xf[3], wa.w, p);
        p = fmaf(xf[4], wb.x, p); p = fmaf(xf[5], wb.y, p);
        p = fmaf(xf[6], wb.z, p); p = fmaf(xf[7], wb.w, p);
        #pragma unroll
        for (int off = 32; off > 0; off >>= 1) p += __shfl_xor(p, off, 64);
        if (lane == 0) F[tb * 8 + k] = p + Bout[k];
    }
}

// ------------- Viterbi: one wave, lane = batch; byte-packed backpointers -------------
__global__ __launch_bounds__(64) void viterbi_k(const float* __restrict__ F,
                                                const float* __restrict__ Trans, // [7][7] next,prev
                                                u64* __restrict__ BP8,           // [256][64]
                                                float* __restrict__ OUT) {       // 16448 floats
    int b = threadIdx.x;
    float tr[KTAG][KTAG];
    #pragma unroll
    for (int n = 0; n < KTAG; ++n)
        #pragma unroll
        for (int p = 0; p < KTAG; ++p)
            tr[n][p] = Trans[n * KTAG + p];

    float v[KTAG];
    #pragma unroll
    for (int k = 0; k < KTAG; ++k) v[k] = (k == 5) ? 0.0f : NEGV;  // START=5

    float cf[KTAG], nf[KTAG];
    #pragma unroll
    for (int n = 0; n < KTAG; ++n) cf[n] = F[b * 8 + n];           // t=0

    for (int t = 0; t < T_LEN; ++t) {
        int tp = (t + 1 < T_LEN) ? t + 1 : t;
        #pragma unroll
        for (int n = 0; n < KTAG; ++n) nf[n] = F[((tp)*BATCH + b) * 8 + n];  // prefetch t+1

        u64 pk = 0;
        float nv[KTAG];
        #pragma unroll
        for (int n = 0; n < KTAG; ++n) {
            float best = v[0] + tr[n][0]; int bi = 0;
            #pragma unroll
            for (int p = 1; p < KTAG; ++p) {
                float s = v[p] + tr[n][p];
                if (s > best) { best = s; bi = p; }   // strict > == np.argmax first-max
            }
            pk |= ((u64)bi) << (8 * n);
            nv[n] = best + cf[n];
        }
        BP8[t * BATCH + b] = pk;
        #pragma unroll
        for (int n = 0; n < KTAG; ++n) { v[n] = nv[n]; cf[n] = nf[n]; }
    }
    float bs = v[0] + tr[6][0]; int tag = 0;          // STOP=6
    #pragma unroll
    for (int k = 1; k < KTAG; ++k) {
        float s = v[k] + tr[6][k];
        if (s > bs) { bs = s; tag = k; }
    }
    OUT[T_LEN * BATCH + b] = bs;                      // path_score [B]
    for (int t = T_LEN - 1; t >= 0; --t) {
        OUT[(size_t)b * T_LEN + t] = (float)tag;      // best_path [B][T]
        tag = (int)((BP8[t * BATCH + b] >> (8 * tag)) & 0xff);
    }
}

extern "C" void kernel_launch(void* const* d_in, const int* in_sizes, int n_in,
                              void* d_out, int out_size, void* d_ws, size_t ws_size,
                              hipStream_t stream) {
    const int*   sent  = (const int*)d_in[0];
    const float* emb   = (const float*)d_in[1];   // [50000][512]
    const float* w_ih  = (const float*)d_in[2];   // [2][2][1024][512]
    const float* w_hh  = (const float*)d_in[3];   // [2][2][1024][256]
    const float* b_ih  = (const float*)d_in[4];   // [2][2][1024]
    const float* b_hh  = (const float*)d_in[5];
    const float* w_out = (const float*)d_in[6];   // [7][512]
    const float* b_out = (const float*)d_in[7];   // [7]
    const float* trans = (const float*)d_in[8];   // [7][7]
    const float* h0    = (const float*)d_in[9];   // [4][64][256]
    const float* c0    = (const float*)d_in[10];
    float* out = (float*)d_out;

    char* ws = (char*)d_ws;
    u16*   xg    = (u16*)(ws);                       // 64 MB  [2][16384][1024] bf16
    u16*   x     = (u16*)(ws + 67108864);            // 16 MB  [16384][512] bf16
    u16*   wihB  = (u16*)(ws + 83886080);            // 4 MB   bf16 w_ih
    uint4* wq    = (uint4*)(ws + 88080384);          // 1 MB   int8 w_hh (packed)
    float* scl   = (float*)(ws + 89128960);          // 16 KB  scales
    float* feats = (float*)(ws + 89145344);          // 512 KB
    u64*   bp8   = (u64*)(ws + 89669632);            // 128 KB

    embed_k<<<16384, 64, 0, stream>>>(sent, emb, x);
    conv_wih<<<1024, 256, 0, stream>>>(w_ih, wihB);
    repack_whh_i8<<<16, 256, 0, stream>>>(w_hh, wq, scl);

    for (int l = 0; l < 2; ++l) {
        gemm_xg<<<dim3(1024, 2), 256, 0, stream>>>(
            x, wihB + (size_t)l * 2 * GDIM * EDIM,
            b_ih + (size_t)l * 2 * GDIM, b_hh + (size_t)l * 2 * GDIM, xg);
        // layer l's weights start at ld=2l; WQ ld-stride = 16384 uint4 -> offset l*32768 (was the R5 bug)
        lstm_scan_i8<<<128, 512, 0, stream>>>(
            xg, wq + (size_t)l * 32768, scl + (size_t)l * 2048,
            h0 + (size_t)l * 2 * BATCH * HDIM, c0 + (size_t)l * 2 * BATCH * HDIM, x);
    }

    feats_k<<<16384, 64, 0, stream>>>(x, w_out, b_out, feats);
    viterbi_k<<<1, 64, 0, stream>>>(feats, trans, bp8, out);
}